// Round 5
// baseline (892.700 us; speedup 1.0000x reference)
//
#include <hip/hip_runtime.h>

// RationalQuadratic: 4-layer MLP conditioner (bf16 MFMA GEMMs) + RQ spline.
// R13: 2-phase software pipeline (T3 minimum recipe) in both GEMM bodies.
// Evidence: fused kernel didn't respond to occupancy (R10) nor staged-byte
// halving (R12) — it is bound by the per-K-step vmcnt(0) drain of the
// stage->barrier->compute structure (m97-ceiling mechanism). Now: BK=32
// tiles double-buffered in the SAME LDS footprint; each iteration does
// {ds_read frags of buf[cur] -> issue next tile's global_load_lds into
// buf[cur^1] -> sched_barrier(0) -> MFMA (setprio-wrapped) -> barrier}.
// Loads get a full compute phase to land; one vmcnt(0)+barrier per tile.
// Geometry unchanged from R12 (mids 128x256, fused 128x192, 512 thr).

typedef __bf16 bf16_t;
typedef __bf16 bf16x8 __attribute__((ext_vector_type(8)));
typedef float f32x4 __attribute__((ext_vector_type(4)));

#define GLOAD_LDS16(g, l)                                               \
  __builtin_amdgcn_global_load_lds(                                     \
      (const __attribute__((address_space(1))) void*)(g),               \
      (__attribute__((address_space(3))) void*)(l), 16, 0, 0)

// ---------------------------------------------------------------------------
// W (K,N) fp32 row-major -> Wt (Npad,K) bf16 row-major. grid (K/64, Npad/64).
__global__ __launch_bounds__(256) void transpose_w(
    const float* __restrict__ W, bf16_t* __restrict__ Wt,
    int K, int N, int Npad) {
  __shared__ float tile[64][65];
  const int kt = blockIdx.x * 64;
  const int nt = blockIdx.y * 64;
  const int r4 = threadIdx.x >> 6;
  const int c = threadIdx.x & 63;
#pragma unroll
  for (int i = 0; i < 16; i++) {
    int r = i * 4 + r4;
    int gn = nt + c;
    tile[r][c] = (gn < N) ? W[(size_t)(kt + r) * N + gn] : 0.0f;
  }
  __syncthreads();
#pragma unroll
  for (int i = 0; i < 16; i++) {
    int r = i * 4 + r4;
    Wt[(size_t)(nt + r) * K + kt + c] = (bf16_t)tile[c][r];
  }
}

// W3 (1024,1472) -> Wt3p (1536,1024) bf16, cols regrouped per-dim with pad:
// padded col n' = d*24 + p (p<23 real, p==23 zero). grid (16, 24).
__global__ __launch_bounds__(256) void transpose_w3p(
    const float* __restrict__ W3, bf16_t* __restrict__ Wt) {
  __shared__ float tile[64][65];
  const int kt = blockIdx.x * 64;
  const int nt = blockIdx.y * 64;
  const int r4 = threadIdx.x >> 6;
  const int c = threadIdx.x & 63;
  const int np = nt + c;
  const int d = np / 24, p = np % 24;
#pragma unroll
  for (int i = 0; i < 16; i++) {
    int r = i * 4 + r4;
    tile[r][c] = (p < 23) ? W3[(size_t)(kt + r) * 1472 + d * 23 + p] : 0.0f;
  }
  __syncthreads();
#pragma unroll
  for (int i = 0; i < 16; i++) {
    int r = i * 4 + r4;
    Wt[(size_t)(nt + r) * 1024 + kt + c] = (bf16_t)tile[c][r];
  }
}

// b3 -> 24-stride padded copy. grid (6,256).
__global__ __launch_bounds__(256) void prep_b3(const float* __restrict__ b3,
                                               float* __restrict__ b3p) {
  int t = blockIdx.x * 256 + threadIdx.x;
  if (t < 1536) {
    int d = t / 24, p = t % 24;
    b3p[t] = (p < 23) ? b3[d * 23 + p] : 0.0f;
  }
}

// ---------------------------------------------------------------------------
// Also zeroes ld_out for this chunk (fused gemm accumulates into it).
__global__ __launch_bounds__(256) void build_x(
    const float* __restrict__ x1, const float* __restrict__ mask1,
    const float* __restrict__ ctx, bf16_t* __restrict__ X,
    float* __restrict__ ld_out, int boff) {
  int idx = blockIdx.x * 256 + threadIdx.x;
  int bl = idx >> 8;
  int c = idx & 255;
  size_t b = (size_t)(boff + bl);
  float v;
  if (c < 64)       v = x1[b * 64 + c];
  else if (c < 128) v = mask1[b * 64 + (c - 64)];
  else              v = ctx[b * 128 + (c - 128)];
  X[(size_t)bl * 256 + c] = (bf16_t)v;
  if (c == 0) ld_out[b] = 0.0f;
}

// ---------------------------------------------------------------------------
// Mid GEMM: 128x256 tile, 8 waves (512 thr) in 2x4, each wave 64x64 (4x4
// frags of 16x16x32 MFMA). R13: BK=32 double-buffered 2-phase pipeline.
// Bank-swizzled LDS (R7): position-quad q holds chunk q ^ ((row>>1)&3).
__global__ __launch_bounds__(512, 4) void gemm_bt(
    const bf16_t* __restrict__ A, const bf16_t* __restrict__ Bt,
    const float* __restrict__ bias, bf16_t* __restrict__ Cout, int N, int K) {
  __shared__ __align__(16) bf16_t As[2][128 * 32];   // 8 KB/buf
  __shared__ __align__(16) bf16_t Bs[2][256 * 32];   // 16 KB/buf
  const int tid = threadIdx.x;
  const int w = tid >> 6;          // 0..7
  const int lane = tid & 63;
  const int m0 = blockIdx.y * 128;
  const int n0 = blockIdx.x * 256;
  const int wm = (w & 1) * 64;
  const int wn = (w >> 1) * 64;    // 0..192
  const int lrow = lane & 15;
  const int quad = lane >> 4;

  // Staging: A-tile 8 chunks/BK32 -> wave w takes chunk w.
  //          B-tile 16 chunks -> wave w takes chunks w and w+8.
  const bf16_t* gA;
  {
    const int byteoff = (w << 10) + lane * 16;
    const int row = byteoff >> 6;
    const int qs = ((byteoff >> 4) & 3) ^ ((row >> 1) & 3);
    gA = A + (size_t)(m0 + row) * K + qs * 8;
  }
  const bf16_t* gB0;
  const bf16_t* gB1;
  {
    int byteoff = (w << 10) + lane * 16;
    int row = byteoff >> 6;
    int qs = ((byteoff >> 4) & 3) ^ ((row >> 1) & 3);
    gB0 = Bt + (size_t)(n0 + row) * K + qs * 8;
    byteoff = ((w + 8) << 10) + lane * 16;
    row = byteoff >> 6;
    qs = ((byteoff >> 4) & 3) ^ ((row >> 1) & 3);
    gB1 = Bt + (size_t)(n0 + row) * K + qs * 8;
  }

  // Hoisted fragment LDS element-offsets (within one BK32 buffer).
  int offA[4], offB[4];
#pragma unroll
  for (int i = 0; i < 4; i++) {
    const int rowA = wm + i * 16 + lrow;
    offA[i] = rowA * 32 + (quad ^ ((rowA >> 1) & 3)) * 8;
    const int rowB = wn + i * 16 + lrow;
    offB[i] = rowB * 32 + (quad ^ ((rowB >> 1) & 3)) * 8;
  }

  f32x4 acc[4][4];
#pragma unroll
  for (int i = 0; i < 4; i++)
#pragma unroll
    for (int j = 0; j < 4; j++) acc[i][j] = (f32x4){0.f, 0.f, 0.f, 0.f};

#define MID_STAGE(NXT)                                                  \
  {                                                                     \
    GLOAD_LDS16(gA, &As[NXT][0] + w * 512);                             \
    GLOAD_LDS16(gB0, &Bs[NXT][0] + w * 512);                            \
    GLOAD_LDS16(gB1, &Bs[NXT][0] + (w + 8) * 512);                      \
    gA += 32; gB0 += 32; gB1 += 32;                                     \
  }

#define MID_STEP(CUR, NXT, DO_STAGE)                                    \
  {                                                                     \
    bf16x8 af[4], bfr[4];                                               \
    _Pragma("unroll") for (int i = 0; i < 4; i++)                       \
      af[i] = *(const bf16x8*)(&As[CUR][0] + offA[i]);                  \
    _Pragma("unroll") for (int j = 0; j < 4; j++)                       \
      bfr[j] = *(const bf16x8*)(&Bs[CUR][0] + offB[j]);                 \
    if (DO_STAGE) MID_STAGE(NXT);                                       \
    __builtin_amdgcn_sched_barrier(0);                                  \
    __builtin_amdgcn_s_setprio(1);                                      \
    _Pragma("unroll") for (int i = 0; i < 4; i++)                       \
      _Pragma("unroll") for (int j = 0; j < 4; j++)                     \
        acc[i][j] = __builtin_amdgcn_mfma_f32_16x16x32_bf16(            \
            af[i], bfr[j], acc[i][j], 0, 0, 0);                         \
    __builtin_amdgcn_s_setprio(0);                                      \
  }

  const int nt = K >> 5;  // BK=32 tiles (even, >= 8)
  MID_STAGE(0);           // prologue: tile 0 -> buf0
  __syncthreads();
  for (int t = 0; t < nt - 2; t += 2) {
    MID_STEP(0, 1, 1);    // compute buf0, stage t+1 -> buf1
    __syncthreads();
    MID_STEP(1, 0, 1);    // compute buf1, stage t+2 -> buf0
    __syncthreads();
  }
  MID_STEP(0, 1, 1);      // compute tile nt-2, stage nt-1 -> buf1
  __syncthreads();
  MID_STEP(1, 0, 0);      // compute tile nt-1
#undef MID_STAGE
#undef MID_STEP

  // C/D layout (m89/m91): col = lane&15, row = quad*4 + reg.
  float bv[4];
#pragma unroll
  for (int j = 0; j < 4; j++) bv[j] = bias[n0 + wn + j * 16 + lrow];
#pragma unroll
  for (int i = 0; i < 4; i++) {
    int rbase = m0 + wm + i * 16 + quad * 4;
#pragma unroll
    for (int j = 0; j < 4; j++) {
      int col = n0 + wn + j * 16 + lrow;
#pragma unroll
      for (int r = 0; r < 4; r++) {
        float v = fmaxf(acc[i][j][r] + bv[j], 0.0f);
        Cout[(size_t)(rbase + r) * N + col] = (bf16_t)v;
      }
    }
  }
}

// ---------------------------------------------------------------------------
// Fused last GEMM + RQ spline. Tile 128 rows x 192 cols (= 8 dims x 24
// padded params). 8 waves 2x4, each wave 64x48 (4x3 frags). R13 pipeline.
// bf16 Pt union (stride 200). LDS layout (elems): As0@0, As1@4096,
// Bs0@8192, Bs1@14336.
__global__ __launch_bounds__(512, 4) void gemm_rq_fused(
    const bf16_t* __restrict__ A, const bf16_t* __restrict__ Bt,
    const float* __restrict__ b3p, const float* __restrict__ x2,
    float* __restrict__ z_out, float* __restrict__ ld_out,
    int boff, int K) {
  union alignas(16) SM {
    struct { bf16_t As[2][128 * 32]; bf16_t Bs[2][192 * 32]; } s;  // 40960 B
    bf16_t Pt[128 * 200];                                          // 51200 B
  };
  __shared__ SM sm;
  const int tid = threadIdx.x;
  const int w = tid >> 6;          // 0..7
  const int lane = tid & 63;
  const int m0 = blockIdx.y * 128;
  const int n0 = blockIdx.x * 192;
  const int wm = (w & 1) * 64;
  const int wn = (w >> 1) * 48;    // 0..144
  const int lrow = lane & 15;
  const int quad = lane >> 4;

  bf16_t* const smB = &sm.s.As[0][0];

  // Staging: A 8 chunks -> wave w chunk w. B 12 chunks -> wave w chunk w;
  // waves 0..3 additionally chunk w+8.
  const bf16_t* gA;
  {
    const int byteoff = (w << 10) + lane * 16;
    const int row = byteoff >> 6;
    const int qs = ((byteoff >> 4) & 3) ^ ((row >> 1) & 3);
    gA = A + (size_t)(m0 + row) * K + qs * 8;
  }
  const bf16_t* gB0;
  const bf16_t* gB1;
  {
    int byteoff = (w << 10) + lane * 16;
    int row = byteoff >> 6;
    int qs = ((byteoff >> 4) & 3) ^ ((row >> 1) & 3);
    gB0 = Bt + (size_t)(n0 + row) * K + qs * 8;
    const int c1 = (w & 3) + 8;              // only used when w < 4
    byteoff = (c1 << 10) + lane * 16;
    row = byteoff >> 6;
    qs = ((byteoff >> 4) & 3) ^ ((row >> 1) & 3);
    gB1 = Bt + (size_t)(n0 + row) * K + qs * 8;
  }

  // Hoisted fragment LDS element-offsets (within one BK32 buffer).
  int offA[4], offB3[3];
#pragma unroll
  for (int i = 0; i < 4; i++) {
    const int rowA = wm + i * 16 + lrow;
    offA[i] = rowA * 32 + (quad ^ ((rowA >> 1) & 3)) * 8;
  }
#pragma unroll
  for (int j = 0; j < 3; j++) {
    const int rowB = wn + j * 16 + lrow;
    offB3[j] = rowB * 32 + (quad ^ ((rowB >> 1) & 3)) * 8;
  }

  f32x4 acc[4][3];
#pragma unroll
  for (int i = 0; i < 4; i++)
#pragma unroll
    for (int j = 0; j < 3; j++) acc[i][j] = (f32x4){0.f, 0.f, 0.f, 0.f};

#define FUS_STAGE(NXT)                                                  \
  {                                                                     \
    GLOAD_LDS16(gA, smB + (NXT) * 4096 + w * 512);                      \
    GLOAD_LDS16(gB0, smB + 8192 + (NXT) * 6144 + w * 512);              \
    gA += 32; gB0 += 32;                                                \
    if (w < 4) {                                                        \
      GLOAD_LDS16(gB1, smB + 8192 + (NXT) * 6144 + ((w & 3) + 8) * 512);\
      gB1 += 32;                                                        \
    }                                                                   \
  }

#define FUS_STEP(CUR, NXT, DO_STAGE)                                    \
  {                                                                     \
    bf16x8 af[4], bfr[3];                                               \
    _Pragma("unroll") for (int i = 0; i < 4; i++)                       \
      af[i] = *(const bf16x8*)(smB + (CUR) * 4096 + offA[i]);           \
    _Pragma("unroll") for (int j = 0; j < 3; j++)                       \
      bfr[j] = *(const bf16x8*)(smB + 8192 + (CUR) * 6144 + offB3[j]);  \
    if (DO_STAGE) FUS_STAGE(NXT);                                       \
    __builtin_amdgcn_sched_barrier(0);                                  \
    __builtin_amdgcn_s_setprio(1);                                      \
    _Pragma("unroll") for (int i = 0; i < 4; i++)                       \
      _Pragma("unroll") for (int j = 0; j < 3; j++)                     \
        acc[i][j] = __builtin_amdgcn_mfma_f32_16x16x32_bf16(            \
            af[i], bfr[j], acc[i][j], 0, 0, 0);                         \
    __builtin_amdgcn_s_setprio(0);                                      \
  }

  const int nt = K >> 5;  // 32 tiles
  FUS_STAGE(0);           // prologue: tile 0 -> buf0
  __syncthreads();
  for (int t = 0; t < nt - 2; t += 2) {
    FUS_STEP(0, 1, 1);
    __syncthreads();
    FUS_STEP(1, 0, 1);
    __syncthreads();
  }
  FUS_STEP(0, 1, 1);
  __syncthreads();
  FUS_STEP(1, 0, 0);
#undef FUS_STAGE
#undef FUS_STEP
  __syncthreads();  // all waves done reading As/Bs before Pt overwrites union

  // --- P-tile (bf16, +bias) into LDS. C/D layout: col=lane&15, row=quad*4+r.
  float bv[3];
#pragma unroll
  for (int j = 0; j < 3; j++) bv[j] = b3p[n0 + wn + j * 16 + lrow];
#pragma unroll
  for (int i = 0; i < 4; i++) {
    const int rbase = wm + i * 16 + quad * 4;
#pragma unroll
    for (int j = 0; j < 3; j++) {
      const int col = wn + j * 16 + lrow;
#pragma unroll
      for (int r = 0; r < 4; r++)
        sm.Pt[(rbase + r) * 200 + col] = (bf16_t)(acc[i][j][r] + bv[j]);
    }
  }
  __syncthreads();

  // --- spline: thread t handles rows (t>>3) and (t>>3)+64, dim t&7.
  const float SHIFT = 0.54132485f;     // log(e-1)
  const float SHIFT_DX = 5.1944682f;   // log(exp(6.0-0.8)-1)
  const float left = -3.0f;
  const float delta_x = 0.8f + log1pf(expf(SHIFT_DX));
  const float right = left + delta_x;
  const float scale = delta_x;
  const int dloc = tid & 7;
  const int dg = blockIdx.x * 8 + dloc;

#pragma unroll
  for (int rr = 0; rr < 2; rr++) {
    const int row = (tid >> 3) + rr * 64;
    const bf16_t* pr = sm.Pt + row * 200 + dloc * 24;
    const size_t bg = (size_t)(boff + m0 + row);
    const float x = x2[bg * 64 + dg];

    // 3x ds_read_b128 (16B-aligned), then statically-indexed registers.
    bf16x8 v0 = *(const bf16x8*)(pr);
    bf16x8 v1 = *(const bf16x8*)(pr + 8);
    bf16x8 v2 = *(const bf16x8*)(pr + 16);
    float pv[24];
#pragma unroll
    for (int j = 0; j < 8; j++) pv[j] = (float)v0[j];
#pragma unroll
    for (int j = 0; j < 8; j++) pv[8 + j] = (float)v1[j];
#pragma unroll
    for (int j = 0; j < 8; j++) pv[16 + j] = (float)v2[j];

    float mw = pv[0];
#pragma unroll
    for (int j = 1; j < 8; j++) mw = fmaxf(mw, pv[j]);
    float ew[8], swv = 0.f;
#pragma unroll
    for (int j = 0; j < 8; j++) { ew[j] = expf(pv[j] - mw); swv += ew[j]; }
    float invw = 1.0f / swv;
    float cw[9];
    cw[0] = left;
    float cum = 0.f;
#pragma unroll
    for (int j = 0; j < 8; j++) {
      cum += 0.1f + 0.2f * ew[j] * invw;
      cw[j + 1] = left + scale * cum;
    }
    float mh = pv[8];
#pragma unroll
    for (int j = 9; j < 16; j++) mh = fmaxf(mh, pv[j]);
    float eh[8], shv = 0.f;
#pragma unroll
    for (int j = 0; j < 8; j++) { eh[j] = expf(pv[8 + j] - mh); shv += eh[j]; }
    float invh = 1.0f / shv;
    float chh[9];
    chh[0] = left;
    float cumh = 0.f;
#pragma unroll
    for (int j = 0; j < 8; j++) {
      cumh += 0.1f + 0.2f * eh[j] * invh;
      chh[j + 1] = left + scale * cumh;
    }
    float dv[9];
    dv[0] = 1.0f;
    dv[8] = 1.0f;
#pragma unroll
    for (int j = 0; j < 7; j++) {
      float v = pv[16 + j] + SHIFT;
      dv[j + 1] = 0.001f + ((v > 20.f) ? v : log1pf(expf(v)));
    }
    int cnt = 0;
#pragma unroll
    for (int j = 0; j < 8; j++) cnt += (cw[j] <= x) ? 1 : 0;
    cnt += ((cw[8] + 1e-6f) <= x) ? 1 : 0;
    int idx = cnt - 1;
    idx = idx < 0 ? 0 : (idx > 7 ? 7 : idx);
    float x_k = cw[0], x_k1 = cw[1], y_k = chh[0], y_k1 = chh[1];
    float d0v = dv[0], d1v = dv[1];
#pragma unroll
    for (int j = 1; j < 8; j++) {
      bool s = (idx == j);
      x_k = s ? cw[j] : x_k;
      x_k1 = s ? cw[j + 1] : x_k1;
      y_k = s ? chh[j] : y_k;
      y_k1 = s ? chh[j + 1] : y_k1;
      d0v = s ? dv[j] : d0v;
      d1v = s ? dv[j + 1] : d1v;
    }
    float x_kd = x_k1 - x_k;
    float y_kd = y_k1 - y_k;
    float s_k = y_kd / x_kd;
    float xi = (x - x_k) / x_kd;
    float xi1m = xi * (1.f - xi);
    float alpha_k = y_kd * (s_k * xi * xi + d0v * xi1m);
    float beta_k = s_k + (d1v + d0v - 2.f * s_k) * xi1m;
    float z_sp = y_k + alpha_k / fmaxf(beta_k, 1e-8f);
    float oxi = 1.f - xi;
    float num = s_k * s_k * (d1v * xi * xi + 2.f * s_k * xi1m + d0v * oxi * oxi);
    float ld_sp = logf(fmaxf(num, 1e-8f)) - 2.f * logf(fmaxf(beta_k, 1e-8f));

    bool inside = (left <= x) && (x < right);
    z_out[bg * 64 + dg] = inside ? z_sp : x;
    float ldv = inside ? ld_sp : 0.f;
    ldv += __shfl_xor(ldv, 1);
    ldv += __shfl_xor(ldv, 2);
    ldv += __shfl_xor(ldv, 4);
    if (dloc == 0) atomicAdd(&ld_out[bg], ldv);
  }
}

// ---------------------------------------------------------------------------
extern "C" void kernel_launch(void* const* d_in, const int* in_sizes, int n_in,
                              void* d_out, int out_size, void* d_ws,
                              size_t ws_size, hipStream_t stream) {
  const float* x1 = (const float*)d_in[0];
  const float* x2 = (const float*)d_in[1];
  const float* ctx = (const float*)d_in[2];
  const float* mask1 = (const float*)d_in[3];
  const float* W0 = (const float*)d_in[4];
  const float* b0 = (const float*)d_in[5];
  const float* W1 = (const float*)d_in[6];
  const float* b1 = (const float*)d_in[7];
  const float* W2 = (const float*)d_in[8];
  const float* b2 = (const float*)d_in[9];
  const float* W3 = (const float*)d_in[10];
  const float* b3 = (const float*)d_in[11];
  float* out = (float*)d_out;

  const int B = 65536;
  char* ws = (char*)d_ws;

  bf16_t* Wt0 = (bf16_t*)ws;                           // 1024x256  (512 KB)
  bf16_t* Wt1 = (bf16_t*)(ws + 524288);                // 1024x1024 (2 MB)
  bf16_t* Wt2 = (bf16_t*)(ws + 524288 + 2097152);      // 1024x1024 (2 MB)
  bf16_t* Wt3 = (bf16_t*)(ws + 524288 + 2 * 2097152);  // 1536x1024 (3 MB)
  float* b3p = (float*)(ws + 524288 + 2 * 2097152 + 3145728);  // 6 KB
  const size_t wend = 524288 + 2 * 2097152 + 3145728 + 8192;

  // Adaptive chunking, prefer C=1. Per-row: HA 2048 B + aliased region
  // 2048 B (X 512 / HB 2048 — lifetimes disjoint; P eliminated by fusion).
  int C = 4;
  if (wend + (size_t)B * 4096 <= ws_size) C = 1;
  else if (wend + (size_t)(B / 2) * 4096 <= ws_size) C = 2;
  const int Bc = B / C;
  bf16_t* HA = (bf16_t*)(ws + wend);
  char* R = ws + wend + (size_t)Bc * 2048;
  bf16_t* X = (bf16_t*)R;
  bf16_t* HB = (bf16_t*)R;
  float* ld_out = out + (size_t)B * 64;

  transpose_w<<<dim3(4, 16), 256, 0, stream>>>(W0, Wt0, 256, 1024, 1024);
  transpose_w<<<dim3(16, 16), 256, 0, stream>>>(W1, Wt1, 1024, 1024, 1024);
  transpose_w<<<dim3(16, 16), 256, 0, stream>>>(W2, Wt2, 1024, 1024, 1024);
  transpose_w3p<<<dim3(16, 24), 256, 0, stream>>>(W3, Wt3);
  prep_b3<<<6, 256, 0, stream>>>(b3, b3p);

  for (int c = 0; c < C; c++) {
    const int boff = c * Bc;
    build_x<<<Bc, 256, 0, stream>>>(x1, mask1, ctx, X, ld_out, boff);
    gemm_bt<<<dim3(4, Bc / 128), 512, 0, stream>>>(X, Wt0, b0, HA, 1024, 256);
    gemm_bt<<<dim3(4, Bc / 128), 512, 0, stream>>>(HA, Wt1, b1, HB, 1024, 1024);
    gemm_bt<<<dim3(4, Bc / 128), 512, 0, stream>>>(HB, Wt2, b2, HA, 1024, 1024);
    gemm_rq_fused<<<dim3(8, Bc / 128), 512, 0, stream>>>(
        HA, Wt3, b3p, x2, out, ld_out, boff, 1024);
  }
}

// Round 6
// 864.175 us; speedup vs baseline: 1.0330x; 1.0330x over previous
//
#include <hip/hip_runtime.h>

// RationalQuadratic: 4-layer MLP conditioner (bf16 MFMA GEMMs) + RQ spline.
// R14: true counted-vmcnt pipeline (T4). R13 failed because __syncthreads
// drains vmcnt(0) every step — loads issued 60-80cy earlier got full-latency
// drained in-step (m218: phase-split with drain0 == no pipeline). Now: raw
// s_barrier + inline-asm counted s_waitcnt, 2-tile lookahead in the SAME
// 2-buffer LDS footprint as R12 (mids 48KB, fused 51.2KB union -> 3-block
// residency kept). Per iter: {vmcnt(L) + barrier (tile t ready, t+1 stays
// in flight) -> ds_read frags -> lgkmcnt(0) + barrier (buf free) -> STAGE
// t+2 into buf[t&1] -> MFMA}. No vmcnt(0) in the steady loop; loads get
// ~1.5 iterations of cover. Fused wave-dependent load count handled with a
// readfirstlane-uniform branch (divergent branch would execute BOTH waits).

typedef __bf16 bf16_t;
typedef __bf16 bf16x8 __attribute__((ext_vector_type(8)));
typedef float f32x4 __attribute__((ext_vector_type(4)));

#define GLOAD_LDS16(g, l)                                               \
  __builtin_amdgcn_global_load_lds(                                     \
      (const __attribute__((address_space(1))) void*)(g),               \
      (__attribute__((address_space(3))) void*)(l), 16, 0, 0)

#define WAITVM(N) asm volatile("s_waitcnt vmcnt(" #N ")" ::: "memory")
#define WAITLGKM0 asm volatile("s_waitcnt lgkmcnt(0)" ::: "memory")
#define SBAR() __builtin_amdgcn_s_barrier()
#define SCHEDB() __builtin_amdgcn_sched_barrier(0)

// ---------------------------------------------------------------------------
// W (K,N) fp32 row-major -> Wt (Npad,K) bf16 row-major. grid (K/64, Npad/64).
__global__ __launch_bounds__(256) void transpose_w(
    const float* __restrict__ W, bf16_t* __restrict__ Wt,
    int K, int N, int Npad) {
  __shared__ float tile[64][65];
  const int kt = blockIdx.x * 64;
  const int nt = blockIdx.y * 64;
  const int r4 = threadIdx.x >> 6;
  const int c = threadIdx.x & 63;
#pragma unroll
  for (int i = 0; i < 16; i++) {
    int r = i * 4 + r4;
    int gn = nt + c;
    tile[r][c] = (gn < N) ? W[(size_t)(kt + r) * N + gn] : 0.0f;
  }
  __syncthreads();
#pragma unroll
  for (int i = 0; i < 16; i++) {
    int r = i * 4 + r4;
    Wt[(size_t)(nt + r) * K + kt + c] = (bf16_t)tile[c][r];
  }
}

// W3 (1024,1472) -> Wt3p (1536,1024) bf16, cols regrouped per-dim with pad:
// padded col n' = d*24 + p (p<23 real, p==23 zero). grid (16, 24).
__global__ __launch_bounds__(256) void transpose_w3p(
    const float* __restrict__ W3, bf16_t* __restrict__ Wt) {
  __shared__ float tile[64][65];
  const int kt = blockIdx.x * 64;
  const int nt = blockIdx.y * 64;
  const int r4 = threadIdx.x >> 6;
  const int c = threadIdx.x & 63;
  const int np = nt + c;
  const int d = np / 24, p = np % 24;
#pragma unroll
  for (int i = 0; i < 16; i++) {
    int r = i * 4 + r4;
    tile[r][c] = (p < 23) ? W3[(size_t)(kt + r) * 1472 + d * 23 + p] : 0.0f;
  }
  __syncthreads();
#pragma unroll
  for (int i = 0; i < 16; i++) {
    int r = i * 4 + r4;
    Wt[(size_t)(nt + r) * 1024 + kt + c] = (bf16_t)tile[c][r];
  }
}

// b3 -> 24-stride padded copy. grid (6,256).
__global__ __launch_bounds__(256) void prep_b3(const float* __restrict__ b3,
                                               float* __restrict__ b3p) {
  int t = blockIdx.x * 256 + threadIdx.x;
  if (t < 1536) {
    int d = t / 24, p = t % 24;
    b3p[t] = (p < 23) ? b3[d * 23 + p] : 0.0f;
  }
}

// ---------------------------------------------------------------------------
// Also zeroes ld_out for this chunk (fused gemm accumulates into it).
__global__ __launch_bounds__(256) void build_x(
    const float* __restrict__ x1, const float* __restrict__ mask1,
    const float* __restrict__ ctx, bf16_t* __restrict__ X,
    float* __restrict__ ld_out, int boff) {
  int idx = blockIdx.x * 256 + threadIdx.x;
  int bl = idx >> 8;
  int c = idx & 255;
  size_t b = (size_t)(boff + bl);
  float v;
  if (c < 64)       v = x1[b * 64 + c];
  else if (c < 128) v = mask1[b * 64 + (c - 64)];
  else              v = ctx[b * 128 + (c - 128)];
  X[(size_t)bl * 256 + c] = (bf16_t)v;
  if (c == 0) ld_out[b] = 0.0f;
}

// ---------------------------------------------------------------------------
// Mid GEMM: 128x256 tile, 8 waves (512 thr) in 2x4, each wave 64x64 (4x4
// frags of 16x16x32 MFMA). R14 counted-vmcnt pipeline, BK=32 double buffer,
// lookahead 2. Bank-swizzled LDS (R7). All addressing hoisted (R11).
__global__ __launch_bounds__(512, 4) void gemm_bt(
    const bf16_t* __restrict__ A, const bf16_t* __restrict__ Bt,
    const float* __restrict__ bias, bf16_t* __restrict__ Cout, int N, int K) {
  __shared__ __align__(16) bf16_t As[2][128 * 32];   // 8 KB/buf
  __shared__ __align__(16) bf16_t Bs[2][256 * 32];   // 16 KB/buf
  const int tid = threadIdx.x;
  const int w = tid >> 6;          // 0..7
  const int lane = tid & 63;
  const int m0 = blockIdx.y * 128;
  const int n0 = blockIdx.x * 256;
  const int wm = (w & 1) * 64;
  const int wn = (w >> 1) * 64;    // 0..192
  const int lrow = lane & 15;
  const int quad = lane >> 4;

  // Staging: per BK=32 tile, A = 8 x 1KB chunks (wave w -> chunk w),
  // B = 16 chunks (wave w -> chunks w, w+8). 3 loads/wave/stage (uniform).
  const bf16_t* gA;
  {
    const int byteoff = (w << 10) + lane * 16;
    const int row = byteoff >> 6;
    const int qs = ((byteoff >> 4) & 3) ^ ((row >> 1) & 3);
    gA = A + (size_t)(m0 + row) * K + qs * 8;
  }
  const bf16_t* gB0;
  const bf16_t* gB1;
  {
    int byteoff = (w << 10) + lane * 16;
    int row = byteoff >> 6;
    int qs = ((byteoff >> 4) & 3) ^ ((row >> 1) & 3);
    gB0 = Bt + (size_t)(n0 + row) * K + qs * 8;
    byteoff = ((w + 8) << 10) + lane * 16;
    row = byteoff >> 6;
    qs = ((byteoff >> 4) & 3) ^ ((row >> 1) & 3);
    gB1 = Bt + (size_t)(n0 + row) * K + qs * 8;
  }

  // Hoisted fragment LDS element-offsets (buffer-local).
  int offA[4], offB[4];
#pragma unroll
  for (int i = 0; i < 4; i++) {
    const int rowA = wm + i * 16 + lrow;
    offA[i] = rowA * 32 + (quad ^ ((rowA >> 1) & 3)) * 8;
    const int rowB = wn + i * 16 + lrow;
    offB[i] = rowB * 32 + (quad ^ ((rowB >> 1) & 3)) * 8;
  }

  f32x4 acc[4][4];
#pragma unroll
  for (int i = 0; i < 4; i++)
#pragma unroll
    for (int j = 0; j < 4; j++) acc[i][j] = (f32x4){0.f, 0.f, 0.f, 0.f};

#define MID_STAGE(BUF)                                                  \
  do {                                                                  \
    GLOAD_LDS16(gA, &As[BUF][0] + w * 512);                             \
    GLOAD_LDS16(gB0, &Bs[BUF][0] + w * 512);                            \
    GLOAD_LDS16(gB1, &Bs[BUF][0] + (w + 8) * 512);                      \
    gA += 32; gB0 += 32; gB1 += 32;                                     \
  } while (0)

  const int nt = K >> 5;  // BK=32 tiles
  MID_STAGE(0);           // tile 0 -> buf0
  MID_STAGE(1);           // tile 1 -> buf1  (2 tiles in flight)
  for (int t = 0; t < nt; t++) {
    const int cur = t & 1;
    // --- tile t ready: drain own tile-t loads, keep tile t+1 in flight.
    if (t + 1 < nt) WAITVM(3); else WAITVM(0);
    SBAR();
    SCHEDB();
    // --- consume buf[cur] into registers.
    bf16x8 af[4], bfr[4];
#pragma unroll
    for (int i = 0; i < 4; i++)
      af[i] = *(const bf16x8*)(&As[cur][0] + offA[i]);
#pragma unroll
    for (int j = 0; j < 4; j++)
      bfr[j] = *(const bf16x8*)(&Bs[cur][0] + offB[j]);
    WAITLGKM0;
    SBAR();               // all waves done reading buf[cur]
    SCHEDB();
    // --- refill buf[cur] with tile t+2; compute overlaps t+1/t+2 loads.
    if (t + 2 < nt) MID_STAGE(cur);
#pragma unroll
    for (int i = 0; i < 4; i++)
#pragma unroll
      for (int j = 0; j < 4; j++)
        acc[i][j] = __builtin_amdgcn_mfma_f32_16x16x32_bf16(
            af[i], bfr[j], acc[i][j], 0, 0, 0);
  }
#undef MID_STAGE

  // C/D layout (m89/m91): col = lane&15, row = quad*4 + reg.
  float bv[4];
#pragma unroll
  for (int j = 0; j < 4; j++) bv[j] = bias[n0 + wn + j * 16 + lrow];
#pragma unroll
  for (int i = 0; i < 4; i++) {
    int rbase = m0 + wm + i * 16 + quad * 4;
#pragma unroll
    for (int j = 0; j < 4; j++) {
      int col = n0 + wn + j * 16 + lrow;
#pragma unroll
      for (int r = 0; r < 4; r++) {
        float v = fmaxf(acc[i][j][r] + bv[j], 0.0f);
        Cout[(size_t)(rbase + r) * N + col] = (bf16_t)v;
      }
    }
  }
}

// ---------------------------------------------------------------------------
// Fused last GEMM + RQ spline. Tile 128 rows x 192 cols (= 8 dims x 24
// padded params). 8 waves 2x4, each wave 64x48 (4x3 frags). R14 pipeline.
// bf16 Pt union (stride 200, 51200B -> 3-block LDS residency kept).
// LDS (elems): As[0]@0, As[1]@4096, Bs[0]@8192, Bs[1]@14336.
__global__ __launch_bounds__(512, 4) void gemm_rq_fused(
    const bf16_t* __restrict__ A, const bf16_t* __restrict__ Bt,
    const float* __restrict__ b3p, const float* __restrict__ x2,
    float* __restrict__ z_out, float* __restrict__ ld_out,
    int boff, int K) {
  union alignas(16) SM {
    struct { bf16_t As[2][128 * 32]; bf16_t Bs[2][192 * 32]; } s;  // 40960 B
    bf16_t Pt[128 * 200];                                          // 51200 B
  };
  __shared__ SM sm;
  const int tid = threadIdx.x;
  const int w = tid >> 6;          // 0..7
  const int lane = tid & 63;
  const int m0 = blockIdx.y * 128;
  const int n0 = blockIdx.x * 192;
  const int wm = (w & 1) * 64;
  const int wn = (w >> 1) * 48;    // 0..144
  const int lrow = lane & 15;
  const int quad = lane >> 4;
  // Scalar (SGPR) wave id: guarantees uniform branches -> only ONE
  // s_waitcnt executes per wave (a divergent if would execute both sides).
  const int wu = __builtin_amdgcn_readfirstlane(w);

  bf16_t* const smB = &sm.s.As[0][0];

  // Staging: A 8 chunks -> wave w chunk w. B 12 chunks -> wave w chunk w;
  // waves 0..3 additionally chunk w+8. Loads/wave/stage: w<4 -> 3, else 2.
  const bf16_t* gA;
  {
    const int byteoff = (w << 10) + lane * 16;
    const int row = byteoff >> 6;
    const int qs = ((byteoff >> 4) & 3) ^ ((row >> 1) & 3);
    gA = A + (size_t)(m0 + row) * K + qs * 8;
  }
  const bf16_t* gB0;
  const bf16_t* gB1;
  {
    int byteoff = (w << 10) + lane * 16;
    int row = byteoff >> 6;
    int qs = ((byteoff >> 4) & 3) ^ ((row >> 1) & 3);
    gB0 = Bt + (size_t)(n0 + row) * K + qs * 8;
    const int c1 = (w & 3) + 8;              // only used when w < 4
    byteoff = (c1 << 10) + lane * 16;
    row = byteoff >> 6;
    qs = ((byteoff >> 4) & 3) ^ ((row >> 1) & 3);
    gB1 = Bt + (size_t)(n0 + row) * K + qs * 8;
  }

  // Hoisted fragment LDS element-offsets (buffer-local).
  int offA[4], offB3[3];
#pragma unroll
  for (int i = 0; i < 4; i++) {
    const int rowA = wm + i * 16 + lrow;
    offA[i] = rowA * 32 + (quad ^ ((rowA >> 1) & 3)) * 8;
  }
#pragma unroll
  for (int j = 0; j < 3; j++) {
    const int rowB = wn + j * 16 + lrow;
    offB3[j] = rowB * 32 + (quad ^ ((rowB >> 1) & 3)) * 8;
  }

  f32x4 acc[4][3];
#pragma unroll
  for (int i = 0; i < 4; i++)
#pragma unroll
    for (int j = 0; j < 3; j++) acc[i][j] = (f32x4){0.f, 0.f, 0.f, 0.f};

#define FUS_STAGE(BUF)                                                  \
  do {                                                                  \
    GLOAD_LDS16(gA, smB + (BUF) * 4096 + w * 512);                      \
    GLOAD_LDS16(gB0, smB + 8192 + (BUF) * 6144 + w * 512);              \
    gA += 32; gB0 += 32;                                                \
    if (wu < 4) {                                                       \
      GLOAD_LDS16(gB1, smB + 8192 + (BUF) * 6144 + ((w & 3) + 8) * 512);\
      gB1 += 32;                                                        \
    }                                                                   \
  } while (0)

  const int nt = K >> 5;  // 32 tiles
  FUS_STAGE(0);
  FUS_STAGE(1);
  for (int t = 0; t < nt; t++) {
    const int cur = t & 1;
    if (t + 1 < nt) {
      if (wu < 4) WAITVM(3); else WAITVM(2);
    } else {
      WAITVM(0);
    }
    SBAR();
    SCHEDB();
    bf16x8 af[4], bfr[3];
#pragma unroll
    for (int i = 0; i < 4; i++)
      af[i] = *(const bf16x8*)(smB + cur * 4096 + offA[i]);
#pragma unroll
    for (int j = 0; j < 3; j++)
      bfr[j] = *(const bf16x8*)(smB + 8192 + cur * 6144 + offB3[j]);
    WAITLGKM0;
    SBAR();
    SCHEDB();
    if (t + 2 < nt) FUS_STAGE(cur);
#pragma unroll
    for (int i = 0; i < 4; i++)
#pragma unroll
      for (int j = 0; j < 3; j++)
        acc[i][j] = __builtin_amdgcn_mfma_f32_16x16x32_bf16(
            af[i], bfr[j], acc[i][j], 0, 0, 0);
  }
#undef FUS_STAGE
  __syncthreads();  // all waves done with As/Bs before Pt overwrites union

  // --- P-tile (bf16, +bias) into LDS. C/D layout: col=lane&15, row=quad*4+r.
  float bv[3];
#pragma unroll
  for (int j = 0; j < 3; j++) bv[j] = b3p[n0 + wn + j * 16 + lrow];
#pragma unroll
  for (int i = 0; i < 4; i++) {
    const int rbase = wm + i * 16 + quad * 4;
#pragma unroll
    for (int j = 0; j < 3; j++) {
      const int col = wn + j * 16 + lrow;
#pragma unroll
      for (int r = 0; r < 4; r++)
        sm.Pt[(rbase + r) * 200 + col] = (bf16_t)(acc[i][j][r] + bv[j]);
    }
  }
  __syncthreads();

  // --- spline: thread t handles rows (t>>3) and (t>>3)+64, dim t&7.
  const float SHIFT = 0.54132485f;     // log(e-1)
  const float SHIFT_DX = 5.1944682f;   // log(exp(6.0-0.8)-1)
  const float left = -3.0f;
  const float delta_x = 0.8f + log1pf(expf(SHIFT_DX));
  const float right = left + delta_x;
  const float scale = delta_x;
  const int dloc = tid & 7;
  const int dg = blockIdx.x * 8 + dloc;

#pragma unroll
  for (int rr = 0; rr < 2; rr++) {
    const int row = (tid >> 3) + rr * 64;
    const bf16_t* pr = sm.Pt + row * 200 + dloc * 24;
    const size_t bg = (size_t)(boff + m0 + row);
    const float x = x2[bg * 64 + dg];

    // 3x ds_read_b128 (16B-aligned), then statically-indexed registers.
    bf16x8 v0 = *(const bf16x8*)(pr);
    bf16x8 v1 = *(const bf16x8*)(pr + 8);
    bf16x8 v2 = *(const bf16x8*)(pr + 16);
    float pv[24];
#pragma unroll
    for (int j = 0; j < 8; j++) pv[j] = (float)v0[j];
#pragma unroll
    for (int j = 0; j < 8; j++) pv[8 + j] = (float)v1[j];
#pragma unroll
    for (int j = 0; j < 8; j++) pv[16 + j] = (float)v2[j];

    float mw = pv[0];
#pragma unroll
    for (int j = 1; j < 8; j++) mw = fmaxf(mw, pv[j]);
    float ew[8], swv = 0.f;
#pragma unroll
    for (int j = 0; j < 8; j++) { ew[j] = expf(pv[j] - mw); swv += ew[j]; }
    float invw = 1.0f / swv;
    float cw[9];
    cw[0] = left;
    float cum = 0.f;
#pragma unroll
    for (int j = 0; j < 8; j++) {
      cum += 0.1f + 0.2f * ew[j] * invw;
      cw[j + 1] = left + scale * cum;
    }
    float mh = pv[8];
#pragma unroll
    for (int j = 9; j < 16; j++) mh = fmaxf(mh, pv[j]);
    float eh[8], shv = 0.f;
#pragma unroll
    for (int j = 0; j < 8; j++) { eh[j] = expf(pv[8 + j] - mh); shv += eh[j]; }
    float invh = 1.0f / shv;
    float chh[9];
    chh[0] = left;
    float cumh = 0.f;
#pragma unroll
    for (int j = 0; j < 8; j++) {
      cumh += 0.1f + 0.2f * eh[j] * invh;
      chh[j + 1] = left + scale * cumh;
    }
    float dv[9];
    dv[0] = 1.0f;
    dv[8] = 1.0f;
#pragma unroll
    for (int j = 0; j < 7; j++) {
      float v = pv[16 + j] + SHIFT;
      dv[j + 1] = 0.001f + ((v > 20.f) ? v : log1pf(expf(v)));
    }
    int cnt = 0;
#pragma unroll
    for (int j = 0; j < 8; j++) cnt += (cw[j] <= x) ? 1 : 0;
    cnt += ((cw[8] + 1e-6f) <= x) ? 1 : 0;
    int idx = cnt - 1;
    idx = idx < 0 ? 0 : (idx > 7 ? 7 : idx);
    float x_k = cw[0], x_k1 = cw[1], y_k = chh[0], y_k1 = chh[1];
    float d0v = dv[0], d1v = dv[1];
#pragma unroll
    for (int j = 1; j < 8; j++) {
      bool s = (idx == j);
      x_k = s ? cw[j] : x_k;
      x_k1 = s ? cw[j + 1] : x_k1;
      y_k = s ? chh[j] : y_k;
      y_k1 = s ? chh[j + 1] : y_k1;
      d0v = s ? dv[j] : d0v;
      d1v = s ? dv[j + 1] : d1v;
    }
    float x_kd = x_k1 - x_k;
    float y_kd = y_k1 - y_k;
    float s_k = y_kd / x_kd;
    float xi = (x - x_k) / x_kd;
    float xi1m = xi * (1.f - xi);
    float alpha_k = y_kd * (s_k * xi * xi + d0v * xi1m);
    float beta_k = s_k + (d1v + d0v - 2.f * s_k) * xi1m;
    float z_sp = y_k + alpha_k / fmaxf(beta_k, 1e-8f);
    float oxi = 1.f - xi;
    float num = s_k * s_k * (d1v * xi * xi + 2.f * s_k * xi1m + d0v * oxi * oxi);
    float ld_sp = logf(fmaxf(num, 1e-8f)) - 2.f * logf(fmaxf(beta_k, 1e-8f));

    bool inside = (left <= x) && (x < right);
    z_out[bg * 64 + dg] = inside ? z_sp : x;
    float ldv = inside ? ld_sp : 0.f;
    ldv += __shfl_xor(ldv, 1);
    ldv += __shfl_xor(ldv, 2);
    ldv += __shfl_xor(ldv, 4);
    if (dloc == 0) atomicAdd(&ld_out[bg], ldv);
  }
}

// ---------------------------------------------------------------------------
extern "C" void kernel_launch(void* const* d_in, const int* in_sizes, int n_in,
                              void* d_out, int out_size, void* d_ws,
                              size_t ws_size, hipStream_t stream) {
  const float* x1 = (const float*)d_in[0];
  const float* x2 = (const float*)d_in[1];
  const float* ctx = (const float*)d_in[2];
  const float* mask1 = (const float*)d_in[3];
  const float* W0 = (const float*)d_in[4];
  const float* b0 = (const float*)d_in[5];
  const float* W1 = (const float*)d_in[6];
  const float* b1 = (const float*)d_in[7];
  const float* W2 = (const float*)d_in[8];
  const float* b2 = (const float*)d_in[9];
  const float* W3 = (const float*)d_in[10];
  const float* b3 = (const float*)d_in[11];
  float* out = (float*)d_out;

  const int B = 65536;
  char* ws = (char*)d_ws;

  bf16_t* Wt0 = (bf16_t*)ws;                           // 1024x256  (512 KB)
  bf16_t* Wt1 = (bf16_t*)(ws + 524288);                // 1024x1024 (2 MB)
  bf16_t* Wt2 = (bf16_t*)(ws + 524288 + 2097152);      // 1024x1024 (2 MB)
  bf16_t* Wt3 = (bf16_t*)(ws + 524288 + 2 * 2097152);  // 1536x1024 (3 MB)
  float* b3p = (float*)(ws + 524288 + 2 * 2097152 + 3145728);  // 6 KB
  const size_t wend = 524288 + 2 * 2097152 + 3145728 + 8192;

  // Adaptive chunking, prefer C=1. Per-row: HA 2048 B + aliased region
  // 2048 B (X 512 / HB 2048 — lifetimes disjoint; P eliminated by fusion).
  int C = 4;
  if (wend + (size_t)B * 4096 <= ws_size) C = 1;
  else if (wend + (size_t)(B / 2) * 4096 <= ws_size) C = 2;
  const int Bc = B / C;
  bf16_t* HA = (bf16_t*)(ws + wend);
  char* R = ws + wend + (size_t)Bc * 2048;
  bf16_t* X = (bf16_t*)R;
  bf16_t* HB = (bf16_t*)R;
  float* ld_out = out + (size_t)B * 64;

  transpose_w<<<dim3(4, 16), 256, 0, stream>>>(W0, Wt0, 256, 1024, 1024);
  transpose_w<<<dim3(16, 16), 256, 0, stream>>>(W1, Wt1, 1024, 1024, 1024);
  transpose_w<<<dim3(16, 16), 256, 0, stream>>>(W2, Wt2, 1024, 1024, 1024);
  transpose_w3p<<<dim3(16, 24), 256, 0, stream>>>(W3, Wt3);
  prep_b3<<<6, 256, 0, stream>>>(b3, b3p);

  for (int c = 0; c < C; c++) {
    const int boff = c * Bc;
    build_x<<<Bc, 256, 0, stream>>>(x1, mask1, ctx, X, ld_out, boff);
    gemm_bt<<<dim3(4, Bc / 128), 512, 0, stream>>>(X, Wt0, b0, HA, 1024, 256);
    gemm_bt<<<dim3(4, Bc / 128), 512, 0, stream>>>(HA, Wt1, b1, HB, 1024, 1024);
    gemm_bt<<<dim3(4, Bc / 128), 512, 0, stream>>>(HB, Wt2, b2, HA, 1024, 1024);
    gemm_rq_fused<<<dim3(8, Bc / 128), 512, 0, stream>>>(
        HA, Wt3, b3p, x2, out, ld_out, boff, 1024);
  }
}

// Round 7
// 812.857 us; speedup vs baseline: 1.0982x; 1.0631x over previous
//
#include <hip/hip_runtime.h>

// RationalQuadratic: 4-layer MLP conditioner (bf16 MFMA GEMMs) + RQ spline.
// R15: revert to R12 (measured best, 819us — R13/R14 pipeline attempts both
// regressed, confirming m131-m141: source-level pipelining of the 2-barrier
// template is neutral-to-negative) + T1 XCD-chunked blockIdx swizzle.
// Mechanism: blocks sharing an A-panel (4 consecutive ids mids, 8 fused)
// round-robin onto DIFFERENT XCDs -> each panel pulled from L3 into 4-8
// L2s. Chunked remap work=(hw&7)*(nwg/8)+(hw>>3) gives each XCD contiguous
// work-ids = whole panels -> panel re-reads become local L2 hits. All grids
// divisible by 8 (2048/2048/4096) so the remap is bijective (ERRATA #11).

typedef __bf16 bf16_t;
typedef __bf16 bf16x8 __attribute__((ext_vector_type(8)));
typedef float f32x4 __attribute__((ext_vector_type(4)));

#define GLOAD_LDS16(g, l)                                               \
  __builtin_amdgcn_global_load_lds(                                     \
      (const __attribute__((address_space(1))) void*)(g),               \
      (__attribute__((address_space(3))) void*)(l), 16, 0, 0)

// Bijective XCD-chunked swizzle (requires nwg % 8 == 0).
__device__ __forceinline__ void xcd_remap(int& bx, int& by) {
  const int gx = gridDim.x;
  const int nwg = gx * gridDim.y;
  const int id = blockIdx.y * gx + blockIdx.x;
  const int nid = (id & 7) * (nwg >> 3) + (id >> 3);
  bx = nid % gx;
  by = nid / gx;
}

// ---------------------------------------------------------------------------
// W (K,N) fp32 row-major -> Wt (Npad,K) bf16 row-major. grid (K/64, Npad/64).
__global__ __launch_bounds__(256) void transpose_w(
    const float* __restrict__ W, bf16_t* __restrict__ Wt,
    int K, int N, int Npad) {
  __shared__ float tile[64][65];
  const int kt = blockIdx.x * 64;
  const int nt = blockIdx.y * 64;
  const int r4 = threadIdx.x >> 6;
  const int c = threadIdx.x & 63;
#pragma unroll
  for (int i = 0; i < 16; i++) {
    int r = i * 4 + r4;
    int gn = nt + c;
    tile[r][c] = (gn < N) ? W[(size_t)(kt + r) * N + gn] : 0.0f;
  }
  __syncthreads();
#pragma unroll
  for (int i = 0; i < 16; i++) {
    int r = i * 4 + r4;
    Wt[(size_t)(nt + r) * K + kt + c] = (bf16_t)tile[c][r];
  }
}

// W3 (1024,1472) -> Wt3p (1536,1024) bf16, cols regrouped per-dim with pad:
// padded col n' = d*24 + p (p<23 real, p==23 zero). grid (16, 24).
__global__ __launch_bounds__(256) void transpose_w3p(
    const float* __restrict__ W3, bf16_t* __restrict__ Wt) {
  __shared__ float tile[64][65];
  const int kt = blockIdx.x * 64;
  const int nt = blockIdx.y * 64;
  const int r4 = threadIdx.x >> 6;
  const int c = threadIdx.x & 63;
  const int np = nt + c;
  const int d = np / 24, p = np % 24;
#pragma unroll
  for (int i = 0; i < 16; i++) {
    int r = i * 4 + r4;
    tile[r][c] = (p < 23) ? W3[(size_t)(kt + r) * 1472 + d * 23 + p] : 0.0f;
  }
  __syncthreads();
#pragma unroll
  for (int i = 0; i < 16; i++) {
    int r = i * 4 + r4;
    Wt[(size_t)(nt + r) * 1024 + kt + c] = (bf16_t)tile[c][r];
  }
}

// b3 -> 24-stride padded copy. grid (6,256).
__global__ __launch_bounds__(256) void prep_b3(const float* __restrict__ b3,
                                               float* __restrict__ b3p) {
  int t = blockIdx.x * 256 + threadIdx.x;
  if (t < 1536) {
    int d = t / 24, p = t % 24;
    b3p[t] = (p < 23) ? b3[d * 23 + p] : 0.0f;
  }
}

// ---------------------------------------------------------------------------
// Also zeroes ld_out for this chunk (fused gemm accumulates into it).
__global__ __launch_bounds__(256) void build_x(
    const float* __restrict__ x1, const float* __restrict__ mask1,
    const float* __restrict__ ctx, bf16_t* __restrict__ X,
    float* __restrict__ ld_out, int boff) {
  int idx = blockIdx.x * 256 + threadIdx.x;
  int bl = idx >> 8;
  int c = idx & 255;
  size_t b = (size_t)(boff + bl);
  float v;
  if (c < 64)       v = x1[b * 64 + c];
  else if (c < 128) v = mask1[b * 64 + (c - 64)];
  else              v = ctx[b * 128 + (c - 128)];
  X[(size_t)bl * 256 + c] = (bf16_t)v;
  if (c == 0) ld_out[b] = 0.0f;
}

// ---------------------------------------------------------------------------
// Mid GEMM: 128x256 tile, 8 waves (512 thr) in 2x4, each wave 64x64 (4x4
// frags of 16x16x32 MFMA). Two BK=32 K-tiles per barrier pair. Bank-swizzled
// LDS (R7): position-quad q holds global k-chunk q ^ ((row>>1)&3). All
// addressing hoisted (R11). XCD-chunked block remap (R15). ReLU epilogue.
__global__ __launch_bounds__(512, 4) void gemm_bt(
    const bf16_t* __restrict__ A, const bf16_t* __restrict__ Bt,
    const float* __restrict__ bias, bf16_t* __restrict__ Cout, int N, int K) {
  __shared__ __align__(16) bf16_t As[2][128 * 32];   // 8 KB/half
  __shared__ __align__(16) bf16_t Bs[2][256 * 32];   // 16 KB/half
  const int tid = threadIdx.x;
  const int w = tid >> 6;          // 0..7
  const int lane = tid & 63;
  int bx, by;
  xcd_remap(bx, by);
  const int m0 = by * 128;
  const int n0 = bx * 256;
  const int wm = (w & 1) * 64;
  const int wn = (w >> 1) * 64;    // 0..192
  const int lrow = lane & 15;
  const int quad = lane >> 4;

  // Staging: A has 8 x 1KB chunks/half -> wave w takes chunk w.
  //          B has 16 chunks/half -> wave w takes chunks w and w+8.
  const bf16_t* gA;
  {
    const int byteoff = (w << 10) + lane * 16;
    const int row = byteoff >> 6;
    const int qs = ((byteoff >> 4) & 3) ^ ((row >> 1) & 3);
    gA = A + (size_t)(m0 + row) * K + qs * 8;
  }
  const bf16_t* gB0;
  const bf16_t* gB1;
  {
    int byteoff = (w << 10) + lane * 16;
    int row = byteoff >> 6;
    int qs = ((byteoff >> 4) & 3) ^ ((row >> 1) & 3);
    gB0 = Bt + (size_t)(n0 + row) * K + qs * 8;
    byteoff = ((w + 8) << 10) + lane * 16;
    row = byteoff >> 6;
    qs = ((byteoff >> 4) & 3) ^ ((row >> 1) & 3);
    gB1 = Bt + (size_t)(n0 + row) * K + qs * 8;
  }
  bf16_t* const dA0 = &As[0][0] + w * 512;          // h=1 at +4096
  bf16_t* const dB0 = &Bs[0][0] + w * 512;          // h=1 at +8192
  bf16_t* const dB1 = &Bs[0][0] + (w + 8) * 512;

  // Hoisted fragment LDS element-offsets.
  int offA[4], offB[4];
#pragma unroll
  for (int i = 0; i < 4; i++) {
    const int rowA = wm + i * 16 + lrow;
    offA[i] = rowA * 32 + (quad ^ ((rowA >> 1) & 3)) * 8;
    const int rowB = wn + i * 16 + lrow;
    offB[i] = rowB * 32 + (quad ^ ((rowB >> 1) & 3)) * 8;
  }

  f32x4 acc[4][4];
#pragma unroll
  for (int i = 0; i < 4; i++)
#pragma unroll
    for (int j = 0; j < 4; j++) acc[i][j] = (f32x4){0.f, 0.f, 0.f, 0.f};

  const int nPair = K >> 6;
  for (int kp = 0; kp < nPair; kp++) {
    GLOAD_LDS16(gA, dA0);
    GLOAD_LDS16(gA + 32, dA0 + 4096);
    GLOAD_LDS16(gB0, dB0);
    GLOAD_LDS16(gB0 + 32, dB0 + 8192);
    GLOAD_LDS16(gB1, dB1);
    GLOAD_LDS16(gB1 + 32, dB1 + 8192);
    gA += 64;
    gB0 += 64;
    gB1 += 64;
    __syncthreads();
#pragma unroll
    for (int h = 0; h < 2; h++) {
      bf16x8 af[4], bfr[4];
#pragma unroll
      for (int i = 0; i < 4; i++)
        af[i] = *(const bf16x8*)(&As[0][0] + h * 4096 + offA[i]);
#pragma unroll
      for (int j = 0; j < 4; j++)
        bfr[j] = *(const bf16x8*)(&Bs[0][0] + h * 8192 + offB[j]);
#pragma unroll
      for (int i = 0; i < 4; i++)
#pragma unroll
        for (int j = 0; j < 4; j++)
          acc[i][j] = __builtin_amdgcn_mfma_f32_16x16x32_bf16(
              af[i], bfr[j], acc[i][j], 0, 0, 0);
    }
    __syncthreads();
  }

  // C/D layout (m89/m91): col = lane&15, row = quad*4 + reg.
  float bv[4];
#pragma unroll
  for (int j = 0; j < 4; j++) bv[j] = bias[n0 + wn + j * 16 + lrow];
#pragma unroll
  for (int i = 0; i < 4; i++) {
    int rbase = m0 + wm + i * 16 + quad * 4;
#pragma unroll
    for (int j = 0; j < 4; j++) {
      int col = n0 + wn + j * 16 + lrow;
#pragma unroll
      for (int r = 0; r < 4; r++) {
        float v = fmaxf(acc[i][j][r] + bv[j], 0.0f);
        Cout[(size_t)(rbase + r) * N + col] = (bf16_t)v;
      }
    }
  }
}

// ---------------------------------------------------------------------------
// Fused last GEMM + RQ spline. Tile 128 rows x 192 cols (= 8 dims x 24
// padded params). 8 waves (512 thr) 2x4, each wave 64x48 (4x3 frags).
// bf16 Pt union (stride 200: 16B-aligned 48B dim-groups; 8-lane dim-groups
// cover all 32 banks disjointly -> conflict-free b128 reads). LDS 51200B.
// XCD-chunked block remap (R15): all 8 N-blocks of an A-panel on one XCD.
__global__ __launch_bounds__(512, 4) void gemm_rq_fused(
    const bf16_t* __restrict__ A, const bf16_t* __restrict__ Bt,
    const float* __restrict__ b3p, const float* __restrict__ x2,
    float* __restrict__ z_out, float* __restrict__ ld_out,
    int boff, int K) {
  union alignas(16) SM {
    struct { bf16_t As[2][128 * 32]; bf16_t Bs[2][192 * 32]; } s;  // 40960 B
    bf16_t Pt[128 * 200];                                          // 51200 B
  };
  __shared__ SM sm;
  const int tid = threadIdx.x;
  const int w = tid >> 6;          // 0..7
  const int lane = tid & 63;
  int bx, by;
  xcd_remap(bx, by);
  const int m0 = by * 128;
  const int n0 = bx * 192;
  const int wm = (w & 1) * 64;
  const int wn = (w >> 1) * 48;    // 0..144
  const int lrow = lane & 15;
  const int quad = lane >> 4;

  bf16_t* const smB = &sm.s.As[0][0];
  // Layout (elems): As[0]@0, As[1]@4096, Bs[0]@8192, Bs[1]@14336.

  // Staging: A 8 chunks/half -> wave w takes chunk w.
  //          B 12 chunks/half -> wave w takes chunk w; w<4 also chunk w+8.
  const bf16_t* gA;
  {
    const int byteoff = (w << 10) + lane * 16;
    const int row = byteoff >> 6;
    const int qs = ((byteoff >> 4) & 3) ^ ((row >> 1) & 3);
    gA = A + (size_t)(m0 + row) * K + qs * 8;
  }
  const bf16_t* gB0;
  const bf16_t* gB1;
  {
    int byteoff = (w << 10) + lane * 16;
    int row = byteoff >> 6;
    int qs = ((byteoff >> 4) & 3) ^ ((row >> 1) & 3);
    gB0 = Bt + (size_t)(n0 + row) * K + qs * 8;
    const int c1 = (w & 3) + 8;              // only used when w < 4
    byteoff = (c1 << 10) + lane * 16;
    row = byteoff >> 6;
    qs = ((byteoff >> 4) & 3) ^ ((row >> 1) & 3);
    gB1 = Bt + (size_t)(n0 + row) * K + qs * 8;
  }
  bf16_t* const dA0 = smB + w * 512;                    // h=1 at +4096
  bf16_t* const dB0 = smB + 8192 + w * 512;             // h=1 at +6144
  bf16_t* const dB1 = smB + 8192 + ((w & 3) + 8) * 512;

  // Hoisted fragment LDS element-offsets.
  int offA[4], offB3[3];
#pragma unroll
  for (int i = 0; i < 4; i++) {
    const int rowA = wm + i * 16 + lrow;
    offA[i] = rowA * 32 + (quad ^ ((rowA >> 1) & 3)) * 8;
  }
#pragma unroll
  for (int j = 0; j < 3; j++) {
    const int rowB = wn + j * 16 + lrow;
    offB3[j] = rowB * 32 + (quad ^ ((rowB >> 1) & 3)) * 8;
  }

  f32x4 acc[4][3];
#pragma unroll
  for (int i = 0; i < 4; i++)
#pragma unroll
    for (int j = 0; j < 3; j++) acc[i][j] = (f32x4){0.f, 0.f, 0.f, 0.f};

  const int nPair = K >> 6;
  for (int kp = 0; kp < nPair; kp++) {
    GLOAD_LDS16(gA, dA0);
    GLOAD_LDS16(gA + 32, dA0 + 4096);
    GLOAD_LDS16(gB0, dB0);
    GLOAD_LDS16(gB0 + 32, dB0 + 6144);
    if (w < 4) {  // wave-uniform
      GLOAD_LDS16(gB1, dB1);
      GLOAD_LDS16(gB1 + 32, dB1 + 6144);
      gB1 += 64;
    }
    gA += 64;
    gB0 += 64;
    __syncthreads();
#pragma unroll
    for (int h = 0; h < 2; h++) {
      bf16x8 af[4], bfr[3];
#pragma unroll
      for (int i = 0; i < 4; i++)
        af[i] = *(const bf16x8*)(smB + h * 4096 + offA[i]);
#pragma unroll
      for (int j = 0; j < 3; j++)
        bfr[j] = *(const bf16x8*)(smB + 8192 + h * 6144 + offB3[j]);
#pragma unroll
      for (int i = 0; i < 4; i++)
#pragma unroll
        for (int j = 0; j < 3; j++)
          acc[i][j] = __builtin_amdgcn_mfma_f32_16x16x32_bf16(
              af[i], bfr[j], acc[i][j], 0, 0, 0);
    }
    __syncthreads();
  }

  // --- P-tile (bf16, +bias) into LDS. Last barrier above guarantees no
  // wave still reads As/Bs. C/D layout: col = lane&15, row = quad*4 + reg.
  float bv[3];
#pragma unroll
  for (int j = 0; j < 3; j++) bv[j] = b3p[n0 + wn + j * 16 + lrow];
#pragma unroll
  for (int i = 0; i < 4; i++) {
    const int rbase = wm + i * 16 + quad * 4;
#pragma unroll
    for (int j = 0; j < 3; j++) {
      const int col = wn + j * 16 + lrow;
#pragma unroll
      for (int r = 0; r < 4; r++)
        sm.Pt[(rbase + r) * 200 + col] = (bf16_t)(acc[i][j][r] + bv[j]);
    }
  }
  __syncthreads();

  // --- spline: thread t handles rows (t>>3) and (t>>3)+64, dim t&7.
  const float SHIFT = 0.54132485f;     // log(e-1)
  const float SHIFT_DX = 5.1944682f;   // log(exp(6.0-0.8)-1)
  const float left = -3.0f;
  const float delta_x = 0.8f + log1pf(expf(SHIFT_DX));
  const float right = left + delta_x;
  const float scale = delta_x;
  const int dloc = tid & 7;
  const int dg = bx * 8 + dloc;

#pragma unroll
  for (int rr = 0; rr < 2; rr++) {
    const int row = (tid >> 3) + rr * 64;
    const bf16_t* pr = sm.Pt + row * 200 + dloc * 24;
    const size_t bg = (size_t)(boff + m0 + row);
    const float x = x2[bg * 64 + dg];

    // 3x ds_read_b128 (16B-aligned), then statically-indexed registers.
    bf16x8 v0 = *(const bf16x8*)(pr);
    bf16x8 v1 = *(const bf16x8*)(pr + 8);
    bf16x8 v2 = *(const bf16x8*)(pr + 16);
    float pv[24];
#pragma unroll
    for (int j = 0; j < 8; j++) pv[j] = (float)v0[j];
#pragma unroll
    for (int j = 0; j < 8; j++) pv[8 + j] = (float)v1[j];
#pragma unroll
    for (int j = 0; j < 8; j++) pv[16 + j] = (float)v2[j];

    float mw = pv[0];
#pragma unroll
    for (int j = 1; j < 8; j++) mw = fmaxf(mw, pv[j]);
    float ew[8], swv = 0.f;
#pragma unroll
    for (int j = 0; j < 8; j++) { ew[j] = expf(pv[j] - mw); swv += ew[j]; }
    float invw = 1.0f / swv;
    float cw[9];
    cw[0] = left;
    float cum = 0.f;
#pragma unroll
    for (int j = 0; j < 8; j++) {
      cum += 0.1f + 0.2f * ew[j] * invw;
      cw[j + 1] = left + scale * cum;
    }
    float mh = pv[8];
#pragma unroll
    for (int j = 9; j < 16; j++) mh = fmaxf(mh, pv[j]);
    float eh[8], shv = 0.f;
#pragma unroll
    for (int j = 0; j < 8; j++) { eh[j] = expf(pv[8 + j] - mh); shv += eh[j]; }
    float invh = 1.0f / shv;
    float chh[9];
    chh[0] = left;
    float cumh = 0.f;
#pragma unroll
    for (int j = 0; j < 8; j++) {
      cumh += 0.1f + 0.2f * eh[j] * invh;
      chh[j + 1] = left + scale * cumh;
    }
    float dv[9];
    dv[0] = 1.0f;
    dv[8] = 1.0f;
#pragma unroll
    for (int j = 0; j < 7; j++) {
      float v = pv[16 + j] + SHIFT;
      dv[j + 1] = 0.001f + ((v > 20.f) ? v : log1pf(expf(v)));
    }
    int cnt = 0;
#pragma unroll
    for (int j = 0; j < 8; j++) cnt += (cw[j] <= x) ? 1 : 0;
    cnt += ((cw[8] + 1e-6f) <= x) ? 1 : 0;
    int idx = cnt - 1;
    idx = idx < 0 ? 0 : (idx > 7 ? 7 : idx);
    float x_k = cw[0], x_k1 = cw[1], y_k = chh[0], y_k1 = chh[1];
    float d0v = dv[0], d1v = dv[1];
#pragma unroll
    for (int j = 1; j < 8; j++) {
      bool s = (idx == j);
      x_k = s ? cw[j] : x_k;
      x_k1 = s ? cw[j + 1] : x_k1;
      y_k = s ? chh[j] : y_k;
      y_k1 = s ? chh[j + 1] : y_k1;
      d0v = s ? dv[j] : d0v;
      d1v = s ? dv[j + 1] : d1v;
    }
    float x_kd = x_k1 - x_k;
    float y_kd = y_k1 - y_k;
    float s_k = y_kd / x_kd;
    float xi = (x - x_k) / x_kd;
    float xi1m = xi * (1.f - xi);
    float alpha_k = y_kd * (s_k * xi * xi + d0v * xi1m);
    float beta_k = s_k + (d1v + d0v - 2.f * s_k) * xi1m;
    float z_sp = y_k + alpha_k / fmaxf(beta_k, 1e-8f);
    float oxi = 1.f - xi;
    float num = s_k * s_k * (d1v * xi * xi + 2.f * s_k * xi1m + d0v * oxi * oxi);
    float ld_sp = logf(fmaxf(num, 1e-8f)) - 2.f * logf(fmaxf(beta_k, 1e-8f));

    bool inside = (left <= x) && (x < right);
    z_out[bg * 64 + dg] = inside ? z_sp : x;
    float ldv = inside ? ld_sp : 0.f;
    ldv += __shfl_xor(ldv, 1);
    ldv += __shfl_xor(ldv, 2);
    ldv += __shfl_xor(ldv, 4);
    if (dloc == 0) atomicAdd(&ld_out[bg], ldv);
  }
}

// ---------------------------------------------------------------------------
extern "C" void kernel_launch(void* const* d_in, const int* in_sizes, int n_in,
                              void* d_out, int out_size, void* d_ws,
                              size_t ws_size, hipStream_t stream) {
  const float* x1 = (const float*)d_in[0];
  const float* x2 = (const float*)d_in[1];
  const float* ctx = (const float*)d_in[2];
  const float* mask1 = (const float*)d_in[3];
  const float* W0 = (const float*)d_in[4];
  const float* b0 = (const float*)d_in[5];
  const float* W1 = (const float*)d_in[6];
  const float* b1 = (const float*)d_in[7];
  const float* W2 = (const float*)d_in[8];
  const float* b2 = (const float*)d_in[9];
  const float* W3 = (const float*)d_in[10];
  const float* b3 = (const float*)d_in[11];
  float* out = (float*)d_out;

  const int B = 65536;
  char* ws = (char*)d_ws;

  bf16_t* Wt0 = (bf16_t*)ws;                           // 1024x256  (512 KB)
  bf16_t* Wt1 = (bf16_t*)(ws + 524288);                // 1024x1024 (2 MB)
  bf16_t* Wt2 = (bf16_t*)(ws + 524288 + 2097152);      // 1024x1024 (2 MB)
  bf16_t* Wt3 = (bf16_t*)(ws + 524288 + 2 * 2097152);  // 1536x1024 (3 MB)
  float* b3p = (float*)(ws + 524288 + 2 * 2097152 + 3145728);  // 6 KB
  const size_t wend = 524288 + 2 * 2097152 + 3145728 + 8192;

  // Adaptive chunking, prefer C=1. Per-row: HA 2048 B + aliased region
  // 2048 B (X 512 / HB 2048 — lifetimes disjoint; P eliminated by fusion).
  int C = 4;
  if (wend + (size_t)B * 4096 <= ws_size) C = 1;
  else if (wend + (size_t)(B / 2) * 4096 <= ws_size) C = 2;
  const int Bc = B / C;
  bf16_t* HA = (bf16_t*)(ws + wend);
  char* R = ws + wend + (size_t)Bc * 2048;
  bf16_t* X = (bf16_t*)R;
  bf16_t* HB = (bf16_t*)R;
  float* ld_out = out + (size_t)B * 64;

  transpose_w<<<dim3(4, 16), 256, 0, stream>>>(W0, Wt0, 256, 1024, 1024);
  transpose_w<<<dim3(16, 16), 256, 0, stream>>>(W1, Wt1, 1024, 1024, 1024);
  transpose_w<<<dim3(16, 16), 256, 0, stream>>>(W2, Wt2, 1024, 1024, 1024);
  transpose_w3p<<<dim3(16, 24), 256, 0, stream>>>(W3, Wt3);
  prep_b3<<<6, 256, 0, stream>>>(b3, b3p);

  for (int c = 0; c < C; c++) {
    const int boff = c * Bc;
    build_x<<<Bc, 256, 0, stream>>>(x1, mask1, ctx, X, ld_out, boff);
    gemm_bt<<<dim3(4, Bc / 128), 512, 0, stream>>>(X, Wt0, b0, HA, 1024, 256);
    gemm_bt<<<dim3(4, Bc / 128), 512, 0, stream>>>(HA, Wt1, b1, HB, 1024, 1024);
    gemm_bt<<<dim3(4, Bc / 128), 512, 0, stream>>>(HB, Wt2, b2, HA, 1024, 1024);
    gemm_rq_fused<<<dim3(8, Bc / 128), 512, 0, stream>>>(
        HA, Wt3, b3p, x2, out, ld_out, boff, 1024);
  }
}